// Round 4
// baseline (393.735 us; speedup 1.0000x reference)
//
#include <hip/hip_runtime.h>

#define NN 4681        // total nodes
#define NI 585         // internal (parent) nodes
#define EH 300
#define H3 900

__device__ __forceinline__ float sigm(float x) { return 1.f / (1.f + expf(-x)); }

// 128x64-tile fp32 GEMM, K=300, K-major LDS (b128 fragment reads).
// C[4681x1200] = gather(embed,tokens) @ [W_ioux|W_fx]; cols<900 -> xiou+b_ioux,
// cols>=900 (rows<585 only) -> fxo+b_fx
__global__ __launch_bounds__(256) void gemm_x_kernel(
    const int* __restrict__ tokens, const float* __restrict__ embed,
    const float* __restrict__ W_ioux, const float* __restrict__ W_fx,
    const float* __restrict__ b_ioux, const float* __restrict__ b_fx,
    float* __restrict__ xiou, float* __restrict__ fxo)
{
  __shared__ float As[16][132];
  __shared__ float Bs[16][68];
  __shared__ int toks[128];
  const int tid = threadIdx.x;
  const int row0 = blockIdx.x * 128;
  const int col0 = blockIdx.y * 64;
  if (col0 >= 960 && row0 >= 640) return;   // pure-fx col tiles only needed for parent rows
  if (tid < 128) {
    int r = row0 + tid;
    toks[tid] = (r < NN) ? tokens[r] : 0;
  }
  float acc[8][4] = {};
  const int trow = (tid >> 4) * 8;
  const int tcol = (tid & 15) * 4;
  const int ar  = tid >> 1;
  const int akh = (tid & 1) * 8;
  const int bk  = tid >> 4;
  const int bc  = (tid & 15) * 4;

  for (int k0 = 0; k0 < 300; k0 += 16) {
    __syncthreads();
    {
      float4 v0 = {0,0,0,0}, v1 = {0,0,0,0};
      const int kb = k0 + akh;
      const float* src = embed + (size_t)toks[ar] * 300;
      if (kb + 3 < 300) v0 = *(const float4*)(src + kb);
      if (kb + 7 < 300) v1 = *(const float4*)(src + kb + 4);
      As[akh+0][ar] = v0.x; As[akh+1][ar] = v0.y; As[akh+2][ar] = v0.z; As[akh+3][ar] = v0.w;
      As[akh+4][ar] = v1.x; As[akh+5][ar] = v1.y; As[akh+6][ar] = v1.z; As[akh+7][ar] = v1.w;
    }
    {
      float4 v = {0,0,0,0};
      const int k = k0 + bk;
      const int col = col0 + bc;
      if (k < 300) {
        if (col < 900)        v = *(const float4*)(W_ioux + (size_t)k * 900 + col);
        else if (col < 1200)  v = *(const float4*)(W_fx + (size_t)k * 300 + (col - 900));
      }
      *(float4*)&Bs[bk][bc] = v;
    }
    __syncthreads();
#pragma unroll
    for (int kk = 0; kk < 16; ++kk) {
      float4 a0 = *(const float4*)&As[kk][trow];
      float4 a1 = *(const float4*)&As[kk][trow + 4];
      float4 b  = *(const float4*)&Bs[kk][tcol];
      float av[8] = {a0.x,a0.y,a0.z,a0.w,a1.x,a1.y,a1.z,a1.w};
      float bv[4] = {b.x,b.y,b.z,b.w};
#pragma unroll
      for (int i = 0; i < 8; ++i)
#pragma unroll
        for (int j = 0; j < 4; ++j) acc[i][j] += av[i] * bv[j];
    }
  }
#pragma unroll
  for (int i = 0; i < 8; ++i) {
    const int grow = row0 + trow + i;
    if (grow >= NN) continue;
#pragma unroll
    for (int j = 0; j < 4; ++j) {
      const int col = col0 + tcol + j;
      float v = acc[i][j];
      if (col < 900)                    xiou[(size_t)grow*900 + col] = v + b_ioux[col];
      else if (col < 1200 && grow < NI) fxo[(size_t)grow*300 + (col-900)] = v + b_fx[col-900];
    }
  }
}

// iou GEMM for internal levels: ioubuf[r][c] = hsb[start+r] @ W_iouh + xiou[start+r] + b_iouh
__global__ __launch_bounds__(256) void gemm_iou(
    int M, int start,
    const float* __restrict__ hsb, const float* __restrict__ xiou,
    const float* __restrict__ W_iouh, const float* __restrict__ b_iouh,
    float* __restrict__ ioubuf)
{
  __shared__ float As[16][132];
  __shared__ float Bs[16][68];
  const int tid = threadIdx.x;
  const int row0 = blockIdx.x * 128;
  const int col0 = blockIdx.y * 64;
  float acc[8][4] = {};
  const int trow = (tid >> 4) * 8;
  const int tcol = (tid & 15) * 4;
  const int ar  = tid >> 1;
  const int akh = (tid & 1) * 8;
  const int bk  = tid >> 4;
  const int bc  = (tid & 15) * 4;

  for (int k0 = 0; k0 < 300; k0 += 16) {
    __syncthreads();
    {
      float4 v0 = {0,0,0,0}, v1 = {0,0,0,0};
      const int grow = row0 + ar;
      const int kb = k0 + akh;
      if (grow < M) {
        const float* src = hsb + (size_t)(start + grow) * 300;
        if (kb + 3 < 300) v0 = *(const float4*)(src + kb);
        if (kb + 7 < 300) v1 = *(const float4*)(src + kb + 4);
      }
      As[akh+0][ar] = v0.x; As[akh+1][ar] = v0.y; As[akh+2][ar] = v0.z; As[akh+3][ar] = v0.w;
      As[akh+4][ar] = v1.x; As[akh+5][ar] = v1.y; As[akh+6][ar] = v1.z; As[akh+7][ar] = v1.w;
    }
    {
      float4 v = {0,0,0,0};
      const int k = k0 + bk;
      const int col = col0 + bc;
      if (k < 300 && col < 900) v = *(const float4*)(W_iouh + (size_t)k * 900 + col);
      *(float4*)&Bs[bk][bc] = v;
    }
    __syncthreads();
#pragma unroll
    for (int kk = 0; kk < 16; ++kk) {
      float4 a0 = *(const float4*)&As[kk][trow];
      float4 a1 = *(const float4*)&As[kk][trow + 4];
      float4 b  = *(const float4*)&Bs[kk][tcol];
      float av[8] = {a0.x,a0.y,a0.z,a0.w,a1.x,a1.y,a1.z,a1.w};
      float bv[4] = {b.x,b.y,b.z,b.w};
#pragma unroll
      for (int i = 0; i < 8; ++i)
#pragma unroll
        for (int j = 0; j < 4; ++j) acc[i][j] += av[i] * bv[j];
    }
  }
#pragma unroll
  for (int i = 0; i < 8; ++i) {
    const int grow = row0 + trow + i;
    if (grow >= M) continue;
#pragma unroll
    for (int j = 0; j < 4; ++j) {
      const int col = col0 + tcol + j;
      if (col < 900)
        ioubuf[(size_t)grow*900 + col] = acc[i][j] + xiou[(size_t)(start+grow)*900 + col] + b_iouh[col];
    }
  }
}

// W_fh GEMM with fused f-gate + fc reduction.
// Thread's 8 acc rows == one parent group (rows 8p'..8p'+7). Writes
// fcb[pstart+p'][col] = sum_i sigm(acc[i]+b_fh+fx) * c_cur[row_i][col]. No atomics.
__global__ __launch_bounds__(256) void gemm_fcb(
    int M, int pstart,
    const float* __restrict__ h_cur, const float* __restrict__ c_cur,
    const float* __restrict__ W_fh, const float* __restrict__ b_fh,
    const float* __restrict__ fxo, float* __restrict__ fcb)
{
  __shared__ float As[16][132];
  __shared__ float Bs[16][68];
  const int tid = threadIdx.x;
  const int row0 = blockIdx.x * 128;
  const int col0 = blockIdx.y * 64;
  float acc[8][4] = {};
  const int trow = (tid >> 4) * 8;
  const int tcol = (tid & 15) * 4;
  const int ar  = tid >> 1;
  const int akh = (tid & 1) * 8;
  const int bk  = tid >> 4;
  const int bc  = (tid & 15) * 4;

  for (int k0 = 0; k0 < 300; k0 += 16) {
    __syncthreads();
    {
      float4 v0 = {0,0,0,0}, v1 = {0,0,0,0};
      const int grow = row0 + ar;
      const int kb = k0 + akh;
      if (grow < M) {
        const float* src = h_cur + (size_t)grow * 300;
        if (kb + 3 < 300) v0 = *(const float4*)(src + kb);
        if (kb + 7 < 300) v1 = *(const float4*)(src + kb + 4);
      }
      As[akh+0][ar] = v0.x; As[akh+1][ar] = v0.y; As[akh+2][ar] = v0.z; As[akh+3][ar] = v0.w;
      As[akh+4][ar] = v1.x; As[akh+5][ar] = v1.y; As[akh+6][ar] = v1.z; As[akh+7][ar] = v1.w;
    }
    {
      float4 v = {0,0,0,0};
      const int k = k0 + bk;
      const int col = col0 + bc;
      if (k < 300 && col < 300) v = *(const float4*)(W_fh + (size_t)k * 300 + col);
      *(float4*)&Bs[bk][bc] = v;
    }
    __syncthreads();
#pragma unroll
    for (int kk = 0; kk < 16; ++kk) {
      float4 a0 = *(const float4*)&As[kk][trow];
      float4 a1 = *(const float4*)&As[kk][trow + 4];
      float4 b  = *(const float4*)&Bs[kk][tcol];
      float av[8] = {a0.x,a0.y,a0.z,a0.w,a1.x,a1.y,a1.z,a1.w};
      float bv[4] = {b.x,b.y,b.z,b.w};
#pragma unroll
      for (int i = 0; i < 8; ++i)
#pragma unroll
        for (int j = 0; j < 4; ++j) acc[i][j] += av[i] * bv[j];
    }
  }
  const int r0 = row0 + trow;
  if (r0 < M) {
    const int p = pstart + (r0 >> 3);
#pragma unroll
    for (int j = 0; j < 4; ++j) {
      const int col = col0 + tcol + j;
      if (col >= 300) continue;
      const float add = b_fh[col] + fxo[(size_t)p*300 + col];
      float fc = 0.f;
#pragma unroll
      for (int i = 0; i < 8; ++i)
        fc += sigm(acc[i][j] + add) * c_cur[(size_t)(r0 + i)*300 + col];
      fcb[(size_t)p*300 + col] = fc;
    }
  }
}

// Gates + h-sum. Block = parent p; children rel-rows 8*bp..8*bp+7.
// leaf: iou = xiou[node]+b_iouh, c = sigm(i)tanh(u)
// internal: iou = ioubuf[rel] (bias pre-added), c += fcb[node]
__global__ __launch_bounds__(256) void gatesum_kernel(
    int pstart, int cstart, int leaf,
    const float* __restrict__ xiou, const float* __restrict__ ioubuf,
    const float* __restrict__ b_iouh, const float* __restrict__ fcb,
    float* __restrict__ h_cur, float* __restrict__ c_cur, float* __restrict__ hsb)
{
  const int bp = blockIdx.x;
  const int p = pstart + bp;
  for (int j = threadIdx.x; j < 300; j += 256) {
    float hsum = 0.f;
#pragma unroll
    for (int k = 0; k < 8; ++k) {
      const int rel = bp * 8 + k;
      const int node = cstart + rel;
      float iv, ov, uv;
      if (leaf) {
        const float* x = xiou + (size_t)node * 900;
        iv = x[j] + b_iouh[j];
        ov = x[300 + j] + b_iouh[300 + j];
        uv = x[600 + j] + b_iouh[600 + j];
      } else {
        const float* x = ioubuf + (size_t)rel * 900;
        iv = x[j]; ov = x[300 + j]; uv = x[600 + j];
      }
      float cc = sigm(iv) * tanhf(uv);
      if (!leaf) cc += fcb[(size_t)node * 300 + j];
      float hh = sigm(ov) * tanhf(cc);
      c_cur[(size_t)rel * 300 + j] = cc;
      h_cur[(size_t)rel * 300 + j] = hh;
      hsum += hh;
    }
    hsb[(size_t)p * 300 + j] = hsum;
  }
}

// Per-node kernel for the last 9 nodes (level of 8, then root).
__global__ __launch_bounds__(256) void level_kernel(
    int start,
    const float* __restrict__ xiou, const float* __restrict__ fxo,
    const float* __restrict__ W_iouh, const float* __restrict__ b_iouh,
    const float* __restrict__ W_fh, const float* __restrict__ b_fh,
    float* __restrict__ hsb, float* __restrict__ fcb,
    const float* __restrict__ W_lin, const float* __restrict__ b_lin,
    float* __restrict__ out)
{
  const int node = start + blockIdx.x;
  const int tid = threadIdx.x;
  __shared__ float hs[EH];
  __shared__ float siou[H3];
  __shared__ float sc[EH];
  __shared__ float sh[EH];

  for (int j = tid; j < EH; j += 256) hs[j] = hsb[(size_t)node * EH + j];
  __syncthreads();

  for (int j = tid; j < H3; j += 256) {
    float acc = xiou[(size_t)node * H3 + j] + b_iouh[j];
    for (int k = 0; k < EH; ++k) acc += hs[k] * W_iouh[k * H3 + j];
    siou[j] = acc;
  }
  __syncthreads();

  for (int j = tid; j < EH; j += 256) {
    float cc = sigm(siou[j]) * tanhf(siou[2 * EH + j]) + fcb[(size_t)node * EH + j];
    sc[j] = cc;
    sh[j] = sigm(siou[EH + j]) * tanhf(cc);
  }
  __syncthreads();

  if (node == 0) {
    for (int j = tid; j < 42; j += 256) {
      float acc = b_lin[j];
      for (int k = 0; k < EH; ++k) acc += sc[k] * W_lin[k * 42 + j];
      out[j] = acc;
    }
    for (int j = tid; j < EH; j += 256) out[42 + j] = sh[j];
    return;
  }

  const int p = (node - 1) >> 3;
  for (int j = tid; j < EH; j += 256) {
    float acc = b_fh[j] + fxo[(size_t)p * EH + j];
    for (int k = 0; k < EH; ++k) acc += sh[k] * W_fh[k * EH + j];
    float f = sigm(acc);
    atomicAdd(&hsb[p * EH + j], sh[j]);
    atomicAdd(&fcb[p * EH + j], f * sc[j]);
  }
}

extern "C" void kernel_launch(void* const* d_in, const int* in_sizes, int n_in,
                              void* d_out, int out_size, void* d_ws, size_t ws_size,
                              hipStream_t stream) {
  const int* tokens   = (const int*)d_in[0];
  const float* embed  = (const float*)d_in[3];
  const float* W_ioux = (const float*)d_in[4];
  const float* b_ioux = (const float*)d_in[5];
  const float* W_iouh = (const float*)d_in[6];
  const float* b_iouh = (const float*)d_in[7];
  const float* W_fx   = (const float*)d_in[8];
  const float* b_fx   = (const float*)d_in[9];
  const float* W_fh   = (const float*)d_in[10];
  const float* b_fh   = (const float*)d_in[11];
  const float* W_lin  = (const float*)d_in[12];
  const float* b_lin  = (const float*)d_in[13];
  float* out = (float*)d_out;

  float* ws     = (float*)d_ws;
  float* xiou   = ws;                                  // NN*900
  float* fxo    = xiou   + (size_t)NN * H3;            // NI*300
  float* hsb    = fxo    + (size_t)NI * EH;            // NI*300
  float* fcb    = hsb    + (size_t)NI * EH;            // NI*300
  float* h_cur  = fcb    + (size_t)NI * EH;            // 4096*300
  float* c_cur  = h_cur  + (size_t)4096 * EH;          // 4096*300
  float* ioubuf = c_cur  + (size_t)4096 * EH;          // 512*900

  // only the root's rows are accumulated by atomics
  hipMemsetAsync(hsb, 0, EH * sizeof(float), stream);
  hipMemsetAsync(fcb, 0, EH * sizeof(float), stream);

  gemm_x_kernel<<<dim3(37, 19), 256, 0, stream>>>(tokens, embed,
      W_ioux, W_fx, b_ioux, b_fx, xiou, fxo);

  // ---- leaf level: 4096 nodes (585..4680), parents 73..584 ----
  gatesum_kernel<<<512, 256, 0, stream>>>(73, 585, 1, xiou, nullptr, b_iouh, nullptr, h_cur, c_cur, hsb);
  gemm_fcb<<<dim3(32, 5), 256, 0, stream>>>(4096, 73, h_cur, c_cur, W_fh, b_fh, fxo, fcb);

  // ---- level 512 (73..584), parents 9..72 ----
  gemm_iou<<<dim3(4, 15), 256, 0, stream>>>(512, 73, hsb, xiou, W_iouh, b_iouh, ioubuf);
  gatesum_kernel<<<64, 256, 0, stream>>>(9, 73, 0, nullptr, ioubuf, b_iouh, fcb, h_cur, c_cur, hsb);
  gemm_fcb<<<dim3(4, 5), 256, 0, stream>>>(512, 9, h_cur, c_cur, W_fh, b_fh, fxo, fcb);

  // ---- level 64 (9..72), parents 1..8 ----
  gemm_iou<<<dim3(1, 15), 256, 0, stream>>>(64, 9, hsb, xiou, W_iouh, b_iouh, ioubuf);
  gatesum_kernel<<<8, 256, 0, stream>>>(1, 9, 0, nullptr, ioubuf, b_iouh, fcb, h_cur, c_cur, hsb);
  gemm_fcb<<<dim3(1, 5), 256, 0, stream>>>(64, 1, h_cur, c_cur, W_fh, b_fh, fxo, fcb);

  // ---- level 8 (1..8) + root ----
  level_kernel<<<8, 256, 0, stream>>>(1, xiou, fxo, W_iouh, b_iouh, W_fh, b_fh, hsb, fcb, W_lin, b_lin, out);
  level_kernel<<<1, 256, 0, stream>>>(0, xiou, fxo, W_iouh, b_iouh, W_fh, b_fh, hsb, fcb, W_lin, b_lin, out);
}